// Round 4
// baseline (179.035 us; speedup 1.0000x reference)
//
#include <hip/hip_runtime.h>
#include <math.h>

typedef unsigned short u16;
typedef __attribute__((ext_vector_type(8))) short short8v;   // 8 bf16
typedef __attribute__((ext_vector_type(4))) float f32x4;

constexpr int B_  = 4;
constexpr int L_  = 8192;
constexpr int D_  = 128;
constexpr int N_  = 32;
constexpr int BL  = B_ * L_;          // 32768 rows
constexpr int CH  = 16;               // part-chunk rows (gemm1 wave = 16 rows)
constexpr int NC  = L_ / CH;          // 512 chunks per batch
constexpr int SCH = 32;               // scan_main rows per block
constexpr int SNC = L_ / SCH;         // 256

// round-to-nearest-even f32 -> bf16
__device__ inline unsigned bfr(float x) {
    unsigned u = __float_as_uint(x);
    return (u + 0x7fffu + ((u >> 16) & 1u)) >> 16;
}
__device__ inline unsigned pkbf(float a, float b) { return bfr(a) | (bfr(b) << 16); }
__device__ inline float b2f(u16 h) { return __uint_as_float(((unsigned)h) << 16); }

// ---------------------------------------------------------------------------
// prep:
//  mode 0: W_eff^T = (W_x[:, :128] @ W_dt)^T -> Wt0 rows 0..127   (bf16 [n][k])
//          lanes over d: W_dt reads coalesced, W_x reads broadcast.
//  mode 1: W_x B/C cols^T -> Wt0 rows 128..191
//  mode 2: W_f^T -> Wt2
//  mode 3..5: conv tap w transposed -> Wtc[w]
//  mode 6: negA = -exp(A_log) * log2(e)   (for exp2-based scan)
// ---------------------------------------------------------------------------
__global__ __launch_bounds__(256) void prep(
    const float* __restrict__ Wx, const float* __restrict__ Wdt,
    const float* __restrict__ Wf, const float* __restrict__ Wconv,
    const float* __restrict__ A_log,
    u16* __restrict__ Wt0, u16* __restrict__ Wt2, u16* __restrict__ Wtc,
    float* __restrict__ negA)
{
    const int which = blockIdx.y;
    const int t = blockIdx.x * 256 + threadIdx.x;
    if (which == 0) {
        if (t >= 128 * 128) return;
        const int k = t >> 7, d = t & 127;        // lanes over d: Wdt coalesced
        float s = 0.f;
        for (int j = 0; j < 128; ++j)
            s = fmaf(Wx[(size_t)k * 192 + j], Wdt[(size_t)j * 128 + d], s);
        Wt0[d * 128 + k] = (u16)bfr(s);
    } else if (which == 1) {
        if (t >= 64 * 128) return;
        const int n = t >> 7, k = t & 127;
        Wt0[(128 + n) * 128 + k] = (u16)bfr(Wx[(size_t)k * 192 + 128 + n]);
    } else if (which == 2) {
        if (t >= 128 * 128) return;
        const int n = t >> 7, k = t & 127;
        Wt2[n * 128 + k] = (u16)bfr(Wf[(size_t)k * 128 + n]);
    } else if (which <= 5) {
        if (t >= 128 * 128) return;
        const int w = which - 3;
        const int n = t >> 7, k = t & 127;
        Wtc[((size_t)w * 128 + n) * 128 + k] = (u16)bfr(Wconv[((size_t)w * 128 + k) * 128 + n]);
    } else {
        if (t < D_ * N_) negA[t] = -expf(A_log[t]) * 1.4426950408889634f;
    }
}

// ---------------------------------------------------------------------------
// gemm1: x(BLx128) @ [W_eff | W_xB | W_xC] (128x192) with fused epilogue:
//   cols 0..127 : delta = softplus(v + b_dt) -> f32 delta, + per-16-row
//                 chunk column-sums -> part
//   cols 128..191: bc[l][j] = B[l][j] * C[l][j]  (product only)
// BM=64, 512 threads = 8 waves (wm 0..3 x wn 0..1), NF=6 per wave.
// ---------------------------------------------------------------------------
__global__ __launch_bounds__(512) void gemm1(
    const float* __restrict__ x, const u16* __restrict__ Wt0,
    const float* __restrict__ b_dt,
    float* __restrict__ delta, float* __restrict__ bc, float* __restrict__ part)
{
    __shared__ __align__(16) u16 Alds[64 * 64];    // 8 KB
    __shared__ __align__(16) u16 Blds[192 * 64];   // 24 KB

    const int tid = threadIdx.x;
    const int r0 = blockIdx.x * 64;                // global row base
    const int wid = tid >> 6, lane = tid & 63;
    const int wm = wid >> 1, wn = wid & 1;
    const int lr = lane & 15, kg = lane >> 4;

    f32x4 acc[6] = {};

    for (int kt = 0; kt < 128; kt += 64) {
        {   // stage A: 64 rows x 64 k, f32->bf16, swizzled
            const int row = tid >> 3, k8 = (tid & 7) * 8;
            const float* src = &x[(size_t)(r0 + row) * 128 + kt + k8];
            const float4 v0 = *reinterpret_cast<const float4*>(src);
            const float4 v1 = *reinterpret_cast<const float4*>(src + 4);
            uint4 p;
            p.x = pkbf(v0.x, v0.y); p.y = pkbf(v0.z, v0.w);
            p.z = pkbf(v1.x, v1.y); p.w = pkbf(v1.z, v1.w);
            *reinterpret_cast<uint4*>(&Alds[row * 64 + (k8 ^ ((row & 7) << 3))]) = p;
        }
        #pragma unroll
        for (int j = 0; j < 3; ++j) {  // stage B: 192 x 64 from bf16 global
            const int g = tid + j * 512;
            const int n = g >> 3, k8 = (g & 7) * 8;
            const uint4 p = *reinterpret_cast<const uint4*>(&Wt0[(size_t)n * 128 + kt + k8]);
            *reinterpret_cast<uint4*>(&Blds[n * 64 + (k8 ^ ((n & 7) << 3))]) = p;
        }
        __syncthreads();
        #pragma unroll
        for (int ks = 0; ks < 2; ++ks) {
            const int k8 = ks * 32 + kg * 8;
            const int row = wm * 16 + lr;
            const short8v af = *reinterpret_cast<const short8v*>(
                &Alds[row * 64 + (k8 ^ ((row & 7) << 3))]);
            #pragma unroll
            for (int nf = 0; nf < 6; ++nf) {
                const int col = wn * 96 + nf * 16 + lr;
                const short8v bf = *reinterpret_cast<const short8v*>(
                    &Blds[col * 64 + (k8 ^ ((col & 7) << 3))]);
                acc[nf] = __builtin_amdgcn_mfma_f32_16x16x32_bf16(af, bf, acc[nf], 0, 0, 0);
            }
        }
        __syncthreads();
    }

    // ---- epilogue ----
    const int nDelta = wn ? 2 : 6;          // frags that are delta columns
    float colsum[6];
    #pragma unroll
    for (int nf = 0; nf < 6; ++nf) {
        if (nf < nDelta) {
            const int col = wn * 96 + nf * 16 + lr;
            const float bb = b_dt[col];
            float s4 = 0.f;
            #pragma unroll
            for (int q = 0; q < 4; ++q) {
                float v = acc[nf][q] + bb;
                v = fmaxf(v, 0.f) + log1pf(expf(-fabsf(v)));   // stable softplus
                const int row = r0 + wm * 16 + kg * 4 + q;
                delta[(size_t)row * 128 + col] = v;
                s4 += v;
            }
            colsum[nf] = s4;
        }
    }
    if (wn) {   // bc product: frag2*frag4 -> j=lr, frag3*frag5 -> j=16+lr
        #pragma unroll
        for (int h = 0; h < 2; ++h)
            #pragma unroll
            for (int q = 0; q < 4; ++q) {
                const int row = r0 + wm * 16 + kg * 4 + q;
                bc[(size_t)row * 32 + h * 16 + lr] = acc[2 + h][q] * acc[4 + h][q];
            }
    }
    // chunk (16-row) column sums -> part
    const int b = r0 / L_;
    const int c = (r0 % L_) / CH + wm;
    #pragma unroll
    for (int nf = 0; nf < 6; ++nf) {
        if (nf < nDelta) {
            float s = colsum[nf];
            s += __shfl_xor(s, 16, 64);
            s += __shfl_xor(s, 32, 64);
            if (kg == 0) {
                const int col = wn * 96 + nf * 16 + lr;
                part[((size_t)b * NC + c) * 128 + col] = s;
            }
        }
    }
}

// ---------------------------------------------------------------------------
// scan_prefix: exclusive prefix over NC=512 chunks per (b,d). grid (B, D).
// ---------------------------------------------------------------------------
__global__ __launch_bounds__(512) void scan_prefix(float* __restrict__ part)
{
    const int b = blockIdx.x, d = blockIdx.y;
    const int c = threadIdx.x, w = c >> 6, lane = c & 63;
    const size_t idx = ((size_t)b * NC + c) * 128 + d;
    const float v = part[idx];
    float s = v;
    #pragma unroll
    for (int off = 1; off < 64; off <<= 1) {
        const float t = __shfl_up(s, off, 64);
        if (lane >= off) s += t;
    }
    __shared__ float wsum[8];
    if (lane == 63) wsum[w] = s;
    __syncthreads();
    float add = 0.f;
    #pragma unroll
    for (int i = 0; i < 8; ++i)
        if (i < w) add += wsum[i];
    part[idx] = s + add - v;   // exclusive
}

// ---------------------------------------------------------------------------
// scan_main (fused with W_f GEMM):
//  phase 1: stage delta tile (32x128 f32), bc tile (32x32 f32)
//  phase 2: per-thread exclusive prefix; p[r] accumulated n4-outer with a4
//           streamed from global (keeps live regs ~35, no reload storm);
//           h -> h_out (f32 global) + h_s (bf16 LDS, swizzled)
//  phase 3: ssm = relu(h @ W_f + b_f) via MFMA, W_f frags straight from L2
// grid (SNC, B), 512 threads.
// ---------------------------------------------------------------------------
__global__ __launch_bounds__(512) void scan_main(
    const float* __restrict__ delta, const float* __restrict__ hprev,
    const float* __restrict__ bc, const float* __restrict__ negA,
    const float* __restrict__ Dp, const float* __restrict__ part,
    const u16* __restrict__ Wt2, const float* __restrict__ b_f,
    float* __restrict__ h_out, u16* __restrict__ ssm)
{
    __shared__ float delta_s[SCH][128];           // 16 KB
    __shared__ float bc_s[SCH][32];               // 4 KB
    __shared__ __align__(16) u16 h_s[SCH * 128];  // 8 KB, swizzled

    const int cb = blockIdx.x, b = blockIdx.y;
    const int tid = threadIdx.x;
    const size_t rowbase = (size_t)b * L_ + (size_t)cb * SCH;

    #pragma unroll
    for (int j = 0; j < 2; ++j) {     // delta tile: 1024 float4
        const int gg = tid + j * 512;
        const int row = gg >> 5, c4 = (gg & 31) * 4;
        *reinterpret_cast<float4*>(&delta_s[row][c4]) =
            *reinterpret_cast<const float4*>(&delta[(rowbase + row) * 128 + c4]);
    }
    if (tid < 256) {                  // bc tile: 256 float4
        const int row = tid >> 3, c4 = (tid & 7) * 4;
        *reinterpret_cast<float4*>(&bc_s[row][c4]) =
            *reinterpret_cast<const float4*>(&bc[(rowbase + row) * 32 + c4]);
    }

    const int d = tid & 127, r0 = tid >> 7;
    const float dp1 = 1.f + Dp[d];
    float hv[8];
    #pragma unroll
    for (int r = 0; r < 8; ++r)
        hv[r] = hprev[(rowbase + r * 4 + r0) * 128 + d];
    const float sbase = part[((size_t)b * NC + cb * 2) * 128 + d];
    __syncthreads();

    float sv[8];
    {
        float s = sbase;
        #pragma unroll
        for (int i = 0; i < 32; ++i) {
            if ((i & 3) == r0) sv[i >> 2] = s;
            s += delta_s[i][d];
        }
    }

    float p[8] = {};
    #pragma unroll 2
    for (int n4 = 0; n4 < 8; ++n4) {
        const float4 a4 = *reinterpret_cast<const float4*>(&negA[d * N_ + n4 * 4]);
        #pragma unroll
        for (int r = 0; r < 8; ++r) {
            const int i = r * 4 + r0;
            const float4 b4 = *reinterpret_cast<const float4*>(&bc_s[i][n4 * 4]);
            const float sr = sv[r];
            const float e0 = exp2f(sr * a4.x);
            const float e1 = exp2f(sr * a4.y);
            const float e2 = exp2f(sr * a4.z);
            const float e3 = exp2f(sr * a4.w);
            float t0 = fmaf(b4.x, e0, b4.y * e1);
            float t1 = fmaf(b4.z, e2, b4.w * e3);
            p[r] += t0 + t1;
        }
    }

    #pragma unroll
    for (int r = 0; r < 8; ++r) {
        const int i = r * 4 + r0;
        const float h = delta_s[i][d] * hv[r] * p[r] * dp1;
        h_out[(rowbase + i) * 128 + d] = h;
        h_s[i * 128 + (((d >> 3) ^ (i & 7)) << 3) + (d & 7)] = (u16)bfr(h);
    }
    __syncthreads();

    // phase 3: (32x128) @ W_f(128x128) + relu -> ssm bf16
    const int wid = tid >> 6, lane = tid & 63;
    const int lr = lane & 15, kg = lane >> 4;
    const int col = wid * 16 + lr;
    f32x4 acc[2] = {};
    #pragma unroll
    for (int ks = 0; ks < 4; ++ks) {
        const int k8 = ks * 32 + kg * 8;
        const short8v bfg = *reinterpret_cast<const short8v*>(&Wt2[(size_t)col * 128 + k8]);
        #pragma unroll
        for (int m = 0; m < 2; ++m) {
            const int row = m * 16 + lr;
            const short8v afg = *reinterpret_cast<const short8v*>(
                &h_s[row * 128 + (k8 ^ ((row & 7) << 3))]);
            acc[m] = __builtin_amdgcn_mfma_f32_16x16x32_bf16(afg, bfg, acc[m], 0, 0, 0);
        }
    }
    const float bb = b_f[col];
    #pragma unroll
    for (int m = 0; m < 2; ++m)
        #pragma unroll
        for (int q = 0; q < 4; ++q) {
            const int row = m * 16 + kg * 4 + q;
            const float v = fmaxf(acc[m][q] + bb, 0.f);
            ssm[(rowbase + row) * 128 + col] = (u16)bfr(v);
        }
}

// ---------------------------------------------------------------------------
// conv_fuse: fused = ssm * relu(causal_conv3(ssm) + conv_b)
// BM=64 (+2 halo), 512 threads = 8 waves (wm 2 x wn 4); weights from L2 into
// VGPRs (24 x 16B loads/thread); grid (L/64, B) = 512 blocks -> 2 blocks/CU.
// ---------------------------------------------------------------------------
__global__ __launch_bounds__(512) void conv_fuse(
    const u16* __restrict__ ssm, const u16* __restrict__ Wtc,
    const float* __restrict__ cbias, float* __restrict__ fused)
{
    __shared__ __align__(16) u16 Alds[66 * 128];   // 16.9 KB, swizzled

    const int tid = threadIdx.x;
    const int bb = blockIdx.y;
    const int r0 = blockIdx.x * 64;                // row within batch
    const u16* sb = ssm + (size_t)bb * L_ * 128;

    #pragma unroll
    for (int j = 0; j < 3; ++j) {   // 66 rows x 16 groups = 1056
        const int g = tid + j * 512;
        if (g < 66 * 16) {
            const int i = g >> 4, k8 = (g & 15) * 8;
            const int gr = r0 - 2 + i;
            uint4 p = make_uint4(0, 0, 0, 0);
            if (gr >= 0)
                p = *reinterpret_cast<const uint4*>(&sb[(size_t)gr * 128 + k8]);
            *reinterpret_cast<uint4*>(&Alds[i * 128 + (k8 ^ ((i & 7) << 3))]) = p;
        }
    }
    __syncthreads();

    const int wid = tid >> 6, lane = tid & 63;
    const int wm = wid >> 2, wn = wid & 3;        // wm 0..1, wn 0..3
    const int lr = lane & 15, kg = lane >> 4;

    f32x4 acc[2][2] = {};
    #pragma unroll
    for (int ks = 0; ks < 4; ++ks) {
        const int k8 = ks * 32 + kg * 8;
        short8v af[2][3];
        #pragma unroll
        for (int m = 0; m < 2; ++m)
            #pragma unroll
            for (int w = 0; w < 3; ++w) {
                const int ri = wm * 32 + m * 16 + lr + w;   // halo-shifted
                af[m][w] = *reinterpret_cast<const short8v*>(
                    &Alds[ri * 128 + (k8 ^ ((ri & 7) << 3))]);
            }
        #pragma unroll
        for (int nf = 0; nf < 2; ++nf) {
            const int col = wn * 32 + nf * 16 + lr;
            #pragma unroll
            for (int w = 0; w < 3; ++w) {
                const short8v bfg = *reinterpret_cast<const short8v*>(
                    &Wtc[((size_t)w * 128 + col) * 128 + k8]);
                acc[0][nf] = __builtin_amdgcn_mfma_f32_16x16x32_bf16(af[0][w], bfg, acc[0][nf], 0, 0, 0);
                acc[1][nf] = __builtin_amdgcn_mfma_f32_16x16x32_bf16(af[1][w], bfg, acc[1][nf], 0, 0, 0);
            }
        }
    }

    #pragma unroll
    for (int nf = 0; nf < 2; ++nf) {
        const int col = wn * 32 + nf * 16 + lr;
        const float bb2 = cbias[col];
        #pragma unroll
        for (int m = 0; m < 2; ++m)
            #pragma unroll
            for (int q = 0; q < 4; ++q) {
                const int row = wm * 32 + m * 16 + kg * 4 + q;
                const int ri = row + 2;
                const u16 sh = Alds[ri * 128 + ((((col >> 3) ^ (ri & 7)) << 3)) + (col & 7)];
                const float cv = fmaxf(acc[m][nf][q] + bb2, 0.f);
                fused[((size_t)bb * L_ + r0 + row) * 128 + col] = b2f(sh) * cv;
            }
    }
}

// ---------------------------------------------------------------------------
extern "C" void kernel_launch(void* const* d_in, const int* in_sizes, int n_in,
                              void* d_out, int out_size, void* d_ws, size_t ws_size,
                              hipStream_t stream)
{
    const float* x      = (const float*)d_in[0];
    const float* hprev  = (const float*)d_in[1];
    const float* A_log  = (const float*)d_in[2];
    const float* Dp     = (const float*)d_in[3];
    const float* W_x    = (const float*)d_in[4];
    const float* W_dt   = (const float*)d_in[5];
    const float* b_dt   = (const float*)d_in[6];
    const float* conv_w = (const float*)d_in[7];
    const float* conv_b = (const float*)d_in[8];
    const float* W_f    = (const float*)d_in[9];
    const float* b_f    = (const float*)d_in[10];

    float* out   = (float*)d_out;                       // fused_output
    float* h_out = out + (size_t)BL * D_;               // h_t

    char* ws = (char*)d_ws;
    float* delta = (float*)ws;                  ws += (size_t)BL * 128 * 4;
    float* bcb   = (float*)ws;                  ws += (size_t)BL * 32 * 4;
    float* part  = (float*)ws;                  ws += (size_t)B_ * NC * 128 * 4;
    float* negA  = (float*)ws;                  ws += (size_t)D_ * N_ * 4;
    u16*   Wt0   = (u16*)ws;                    ws += (size_t)192 * 128 * 2;
    u16*   Wt2   = (u16*)ws;                    ws += (size_t)128 * 128 * 2;
    u16*   Wtc   = (u16*)ws;                    ws += (size_t)3 * 128 * 128 * 2;
    u16*   ssm   = (u16*)ws;

    prep<<<dim3(64, 7), dim3(256), 0, stream>>>(
        W_x, W_dt, W_f, conv_w, A_log, Wt0, Wt2, Wtc, negA);
    gemm1<<<dim3(BL / 64), dim3(512), 0, stream>>>(
        x, Wt0, b_dt, delta, bcb, part);
    scan_prefix<<<dim3(B_, D_), dim3(512), 0, stream>>>(part);
    scan_main<<<dim3(SNC, B_), dim3(512), 0, stream>>>(
        delta, hprev, bcb, negA, Dp, part, Wt2, b_f, h_out, ssm);
    conv_fuse<<<dim3(L_ / 64, B_), dim3(512), 0, stream>>>(
        ssm, Wtc, conv_b, out);
}